// Round 1
// baseline (387.482 us; speedup 1.0000x reference)
//
#include <hip/hip_runtime.h>
#include <hip/hip_bf16.h>

// GraphSAGE 2-layer forward on MI355X.
// Strategy: build CSR once (deg count -> hierarchical scan -> cursor fill),
// then wave-per-node mean-aggregation (no float atomics), then fp32 tiled
// dual-GEMM (agg@W_l + x@W_r + b) with A tiles in LDS.

#define BLK 256

// ---------------- CSR build ----------------

__global__ __launch_bounds__(BLK) void deg_count_kernel(const int* __restrict__ dst,
                                                        int E, int* __restrict__ deg) {
    int e = blockIdx.x * BLK + threadIdx.x;
    if (e < E) atomicAdd(&deg[dst[e]], 1);
}

__global__ __launch_bounds__(BLK) void partial_sum_kernel(const int* __restrict__ deg,
                                                          int n, int* __restrict__ partials) {
    __shared__ int s[BLK];
    int t = threadIdx.x;
    int idx = blockIdx.x * BLK + t;
    s[t] = (idx < n) ? deg[idx] : 0;
    __syncthreads();
    for (int o = BLK / 2; o > 0; o >>= 1) {
        if (t < o) s[t] += s[t + o];
        __syncthreads();
    }
    if (t == 0) partials[blockIdx.x] = s[0];
}

// exclusive scan of `n` (<=256) partials, in place
__global__ __launch_bounds__(BLK) void scan_partials_kernel(int* __restrict__ partials, int n) {
    __shared__ int s[BLK];
    int t = threadIdx.x;
    int v = (t < n) ? partials[t] : 0;
    s[t] = v;
    __syncthreads();
    int sum = v;
    for (int o = 1; o < BLK; o <<= 1) {
        int other = (t >= o) ? s[t - o] : 0;
        __syncthreads();
        sum += other;
        s[t] = sum;
        __syncthreads();
    }
    if (t < n) partials[t] = sum - v;  // exclusive
}

__global__ __launch_bounds__(BLK) void chunk_scan_kernel(const int* __restrict__ deg,
                                                         const int* __restrict__ partials,
                                                         int n, int* __restrict__ row_start) {
    __shared__ int s[BLK];
    int t = threadIdx.x;
    int idx = blockIdx.x * BLK + t;
    int v = (idx < n) ? deg[idx] : 0;
    s[t] = v;
    __syncthreads();
    int sum = v;
    for (int o = 1; o < BLK; o <<= 1) {
        int other = (t >= o) ? s[t - o] : 0;
        __syncthreads();
        sum += other;
        s[t] = sum;
        __syncthreads();
    }
    if (idx < n) row_start[idx] = (sum - v) + partials[blockIdx.x];
}

__global__ __launch_bounds__(BLK) void fill_kernel(const int* __restrict__ src,
                                                   const int* __restrict__ dst, int E,
                                                   const int* __restrict__ row_start,
                                                   int* __restrict__ cursor,
                                                   int* __restrict__ csr_src) {
    int e = blockIdx.x * BLK + threadIdx.x;
    if (e >= E) return;
    int d = dst[e];
    int pos = atomicAdd(&cursor[d], 1);
    csr_src[row_start[d] + pos] = src[e];
}

// ---------------- mean aggregation: one wave per node ----------------
// feat: [n,128] f32; out: [n,128] f32 = (sum of neighbor rows)/max(deg,1)

__global__ __launch_bounds__(BLK) void agg_kernel(const float* __restrict__ feat,
                                                  const int* __restrict__ row_start,
                                                  const int* __restrict__ deg,
                                                  const int* __restrict__ csr_src,
                                                  float* __restrict__ out, int n_nodes) {
    int gid = blockIdx.x * (BLK / 64) + (threadIdx.x >> 6);
    int lane = threadIdx.x & 63;
    if (gid >= n_nodes) return;
    int start = row_start[gid];
    int cnt = deg[gid];
    const float2* fp = (const float2*)feat;
    float ax0 = 0.f, ay0 = 0.f, ax1 = 0.f, ay1 = 0.f;
    int e = 0;
    for (; e + 2 <= cnt; e += 2) {
        int s0 = csr_src[start + e];
        int s1 = csr_src[start + e + 1];
        float2 v0 = fp[(size_t)s0 * 64 + lane];
        float2 v1 = fp[(size_t)s1 * 64 + lane];
        ax0 += v0.x; ay0 += v0.y;
        ax1 += v1.x; ay1 += v1.y;
    }
    if (e < cnt) {
        int s0 = csr_src[start + e];
        float2 v0 = fp[(size_t)s0 * 64 + lane];
        ax0 += v0.x; ay0 += v0.y;
    }
    float inv = 1.0f / fmaxf((float)cnt, 1.0f);
    float2 r;
    r.x = (ax0 + ax1) * inv;
    r.y = (ay0 + ay1) * inv;
    ((float2*)out)[(size_t)gid * 64 + lane] = r;
}

// ---------------- dual GEMM: out = A1@Wl + A2@Wr + bias (opt ReLU) ----------------
// A1,A2: [M,128] f32; Wl,Wr: [128,NCOL] row-major; out: [M,NCOL]

template <int NCOL, bool RELU>
__global__ __launch_bounds__(BLK) void gemm_dual_kernel(const float* __restrict__ A1,
                                                        const float* __restrict__ A2,
                                                        const float* __restrict__ Wl,
                                                        const float* __restrict__ Wr,
                                                        const float* __restrict__ bias,
                                                        float* __restrict__ out, int M) {
    constexpr int TM = 64;
    constexpr int CG = NCOL / 4;   // col groups of 4
    constexpr int TY = BLK / CG;   // row groups
    constexpr int RPT = TM / TY;   // rows per thread
    __shared__ float sA1[TM][128];
    __shared__ float sA2[TM][128];

    const int t = threadIdx.x;
    const int brow = blockIdx.x * TM;

    // stage A tiles (guarded for the 50000 % 64 tail)
#pragma unroll
    for (int i = 0; i < (TM * 128 / 4) / BLK; i++) {  // 8 float4 per thread per matrix
        int id = t + BLK * i;
        int r = id >> 5, c4 = id & 31;
        int g = brow + r;
        float4 v1 = make_float4(0.f, 0.f, 0.f, 0.f);
        float4 v2 = v1;
        if (g < M) {
            v1 = ((const float4*)(A1 + (size_t)g * 128))[c4];
            v2 = ((const float4*)(A2 + (size_t)g * 128))[c4];
        }
        ((float4*)sA1)[id] = v1;
        ((float4*)sA2)[id] = v2;
    }
    __syncthreads();

    const int tx = t % CG, ty = t / CG;
    const int j0 = tx * 4, r0 = ty * RPT;

    float4 acc[RPT];
#pragma unroll
    for (int i = 0; i < RPT; i++) acc[i] = make_float4(0.f, 0.f, 0.f, 0.f);

#pragma unroll 2
    for (int k = 0; k < 128; k += 2) {
        float4 wl0 = *(const float4*)(Wl + (size_t)k * NCOL + j0);
        float4 wr0 = *(const float4*)(Wr + (size_t)k * NCOL + j0);
        float4 wl1 = *(const float4*)(Wl + (size_t)(k + 1) * NCOL + j0);
        float4 wr1 = *(const float4*)(Wr + (size_t)(k + 1) * NCOL + j0);
#pragma unroll
        for (int i = 0; i < RPT; i++) {
            float2 a = *(const float2*)&sA1[r0 + i][k];
            float2 b = *(const float2*)&sA2[r0 + i][k];
            acc[i].x = fmaf(a.x, wl0.x, fmaf(b.x, wr0.x, fmaf(a.y, wl1.x, fmaf(b.y, wr1.x, acc[i].x))));
            acc[i].y = fmaf(a.x, wl0.y, fmaf(b.x, wr0.y, fmaf(a.y, wl1.y, fmaf(b.y, wr1.y, acc[i].y))));
            acc[i].z = fmaf(a.x, wl0.z, fmaf(b.x, wr0.z, fmaf(a.y, wl1.z, fmaf(b.y, wr1.z, acc[i].z))));
            acc[i].w = fmaf(a.x, wl0.w, fmaf(b.x, wr0.w, fmaf(a.y, wl1.w, fmaf(b.y, wr1.w, acc[i].w))));
        }
    }

    float4 bv = *(const float4*)(bias + j0);
#pragma unroll
    for (int i = 0; i < RPT; i++) {
        int g = brow + r0 + i;
        if (g < M) {
            float4 o;
            o.x = acc[i].x + bv.x;
            o.y = acc[i].y + bv.y;
            o.z = acc[i].z + bv.z;
            o.w = acc[i].w + bv.w;
            if (RELU) {
                o.x = fmaxf(o.x, 0.f);
                o.y = fmaxf(o.y, 0.f);
                o.z = fmaxf(o.z, 0.f);
                o.w = fmaxf(o.w, 0.f);
            }
            *(float4*)(out + (size_t)g * NCOL + j0) = o;
        }
    }
}

// ---------------- launch ----------------

extern "C" void kernel_launch(void* const* d_in, const int* in_sizes, int n_in,
                              void* d_out, int out_size, void* d_ws, size_t ws_size,
                              hipStream_t stream) {
    const float* x   = (const float*)d_in[0];
    const int*   ei  = (const int*)d_in[1];
    const float* W1l = (const float*)d_in[2];
    const float* W1r = (const float*)d_in[3];
    const float* b1  = (const float*)d_in[4];
    const float* W2l = (const float*)d_in[5];
    const float* W2r = (const float*)d_in[6];
    const float* b2  = (const float*)d_in[7];
    float* out = (float*)d_out;

    const int N = in_sizes[0] / 128;  // 50000
    const int E = in_sizes[1] / 2;    // 800000
    const int* src = ei;
    const int* dst = ei + E;

    // workspace carve-up (256B aligned)
    char* ws = (char*)d_ws;
    size_t off = 0;
    auto carve = [&](size_t bytes) {
        void* p = ws + off;
        off += (bytes + 255) & ~(size_t)255;
        return p;
    };
    int* deg       = (int*)carve((size_t)N * 4);
    int* cursor    = (int*)carve((size_t)N * 4);
    int* row_start = (int*)carve((size_t)N * 4);
    int* partials  = (int*)carve(256 * 4);
    int* csr_src   = (int*)carve((size_t)E * 4);
    float* agg     = (float*)carve((size_t)N * 128 * 4);
    float* h       = (float*)carve((size_t)N * 128 * 4);

    hipMemsetAsync(deg, 0, (size_t)N * 4, stream);
    hipMemsetAsync(cursor, 0, (size_t)N * 4, stream);

    const int nchunk = (N + BLK - 1) / BLK;  // 196 (<=256 required)
    deg_count_kernel<<<(E + BLK - 1) / BLK, BLK, 0, stream>>>(dst, E, deg);
    partial_sum_kernel<<<nchunk, BLK, 0, stream>>>(deg, N, partials);
    scan_partials_kernel<<<1, BLK, 0, stream>>>(partials, nchunk);
    chunk_scan_kernel<<<nchunk, BLK, 0, stream>>>(deg, partials, N, row_start);
    fill_kernel<<<(E + BLK - 1) / BLK, BLK, 0, stream>>>(src, dst, E, row_start, cursor, csr_src);

    const int aggGrid = (N + 3) / 4;  // 4 waves (nodes) per 256-thread block
    const int gemmGrid = (N + 63) / 64;

    // layer 1
    agg_kernel<<<aggGrid, BLK, 0, stream>>>(x, row_start, deg, csr_src, agg, N);
    gemm_dual_kernel<128, true><<<gemmGrid, BLK, 0, stream>>>(agg, x, W1l, W1r, b1, h, N);
    // layer 2 (same graph, reuse deg/row_start/csr_src; reuse agg buffer)
    agg_kernel<<<aggGrid, BLK, 0, stream>>>(h, row_start, deg, csr_src, agg, N);
    gemm_dual_kernel<64, false><<<gemmGrid, BLK, 0, stream>>>(agg, h, W2l, W2r, b2, out, N);
}

// Round 2
// 298.568 us; speedup vs baseline: 1.2978x; 1.2978x over previous
//
#include <hip/hip_runtime.h>
#include <hip/hip_bf16.h>

// GraphSAGE 2-layer forward on MI355X — round 2.
// bf16 data path + MFMA GEMM (no LDS), CSR-based mean aggregation in bf16.

#define BLK 256

typedef __attribute__((ext_vector_type(8))) short short8;
typedef __attribute__((ext_vector_type(4))) float f32x4;

__device__ inline unsigned short f2bf(float f) {
    unsigned int u = __builtin_bit_cast(unsigned int, f);
    u += 0x7fffu + ((u >> 16) & 1u);  // RNE (ignoring NaN edge; inputs are finite)
    return (unsigned short)(u >> 16);
}
__device__ inline float bf2f(unsigned short h) {
    return __builtin_bit_cast(float, ((unsigned int)h) << 16);
}

// ---------------- CSR build ----------------

__global__ __launch_bounds__(BLK) void deg_count_kernel(const int* __restrict__ dst,
                                                        int E, int* __restrict__ deg) {
    int e = blockIdx.x * BLK + threadIdx.x;
    if (e < E) atomicAdd(&deg[dst[e]], 1);
}

__global__ __launch_bounds__(BLK) void partial_sum_kernel(const int* __restrict__ deg,
                                                          int n, int* __restrict__ partials) {
    __shared__ int s[BLK];
    int t = threadIdx.x;
    int idx = blockIdx.x * BLK + t;
    s[t] = (idx < n) ? deg[idx] : 0;
    __syncthreads();
    for (int o = BLK / 2; o > 0; o >>= 1) {
        if (t < o) s[t] += s[t + o];
        __syncthreads();
    }
    if (t == 0) partials[blockIdx.x] = s[0];
}

__global__ __launch_bounds__(BLK) void scan_partials_kernel(int* __restrict__ partials, int n) {
    __shared__ int s[BLK];
    int t = threadIdx.x;
    int v = (t < n) ? partials[t] : 0;
    s[t] = v;
    __syncthreads();
    int sum = v;
    for (int o = 1; o < BLK; o <<= 1) {
        int other = (t >= o) ? s[t - o] : 0;
        __syncthreads();
        sum += other;
        s[t] = sum;
        __syncthreads();
    }
    if (t < n) partials[t] = sum - v;  // exclusive
}

__global__ __launch_bounds__(BLK) void chunk_scan_kernel(const int* __restrict__ deg,
                                                         const int* __restrict__ partials,
                                                         int n, int* __restrict__ row_start) {
    __shared__ int s[BLK];
    int t = threadIdx.x;
    int idx = blockIdx.x * BLK + t;
    int v = (idx < n) ? deg[idx] : 0;
    s[t] = v;
    __syncthreads();
    int sum = v;
    for (int o = 1; o < BLK; o <<= 1) {
        int other = (t >= o) ? s[t - o] : 0;
        __syncthreads();
        sum += other;
        s[t] = sum;
        __syncthreads();
    }
    if (idx < n) row_start[idx] = (sum - v) + partials[blockIdx.x];
}

__global__ __launch_bounds__(BLK) void fill_kernel(const int* __restrict__ src,
                                                   const int* __restrict__ dst, int E,
                                                   const int* __restrict__ row_start,
                                                   int* __restrict__ cursor,
                                                   int* __restrict__ csr_src) {
    int e = blockIdx.x * BLK + threadIdx.x;
    if (e >= E) return;
    int d = dst[e];
    int pos = atomicAdd(&cursor[d], 1);
    csr_src[row_start[d] + pos] = src[e];
}

// ---------------- conversions / weight packing ----------------

// f32 -> bf16, 4 elements per thread
__global__ __launch_bounds__(BLK) void f32_to_bf16_kernel(const float* __restrict__ in,
                                                          unsigned short* __restrict__ out,
                                                          int nquad) {
    int i = blockIdx.x * BLK + threadIdx.x;
    if (i >= nquad) return;
    float4 v = ((const float4*)in)[i];
    ushort4 o;
    o.x = f2bf(v.x); o.y = f2bf(v.y); o.z = f2bf(v.z); o.w = f2bf(v.w);
    ((ushort4*)out)[i] = o;
}

// Pack W [K][Ncol] row-major f32 into MFMA B-fragment order (bf16):
// P[((kb*(Ncol/16)+n16)*64 + lane)*8 + j] = W[kb*32 + (lane>>4)*8 + j][n16*16 + (lane&15)]
__global__ __launch_bounds__(BLK) void pack_w_kernel(const float* __restrict__ W,
                                                     unsigned short* __restrict__ P,
                                                     int K, int Ncol) {
    int t = blockIdx.x * BLK + threadIdx.x;
    if (t >= K * Ncol) return;
    int j = t & 7;
    int lane = (t >> 3) & 63;
    int rest = t >> 9;
    int nt = Ncol >> 4;
    int n16 = rest % nt, kb = rest / nt;
    int k = kb * 32 + (lane >> 4) * 8 + j;
    int c = n16 * 16 + (lane & 15);
    P[t] = f2bf(W[(size_t)k * Ncol + c]);
}

// ---------------- mean aggregation (bf16): one wave per node ----------------

__global__ __launch_bounds__(BLK) void agg_bf16_kernel(const unsigned short* __restrict__ feat,
                                                       const int* __restrict__ row_start,
                                                       const int* __restrict__ deg,
                                                       const int* __restrict__ csr_src,
                                                       unsigned short* __restrict__ out,
                                                       int n_nodes) {
    int gid = blockIdx.x * (BLK / 64) + (threadIdx.x >> 6);
    int lane = threadIdx.x & 63;
    if (gid >= n_nodes) return;
    int start = row_start[gid];
    int cnt = deg[gid];
    const unsigned int* fp = (const unsigned int*)feat;  // 2 bf16 per uint, 64 uints/row
    float a0 = 0.f, a1 = 0.f, b0 = 0.f, b1 = 0.f;
    float c0 = 0.f, c1 = 0.f, d0 = 0.f, d1 = 0.f;
    int e = 0;
    for (; e + 4 <= cnt; e += 4) {
        int s0 = csr_src[start + e];
        int s1 = csr_src[start + e + 1];
        int s2 = csr_src[start + e + 2];
        int s3 = csr_src[start + e + 3];
        unsigned int v0 = fp[(size_t)s0 * 64 + lane];
        unsigned int v1 = fp[(size_t)s1 * 64 + lane];
        unsigned int v2 = fp[(size_t)s2 * 64 + lane];
        unsigned int v3 = fp[(size_t)s3 * 64 + lane];
        a0 += bf2f((unsigned short)v0); a1 += bf2f((unsigned short)(v0 >> 16));
        b0 += bf2f((unsigned short)v1); b1 += bf2f((unsigned short)(v1 >> 16));
        c0 += bf2f((unsigned short)v2); c1 += bf2f((unsigned short)(v2 >> 16));
        d0 += bf2f((unsigned short)v3); d1 += bf2f((unsigned short)(v3 >> 16));
    }
    for (; e < cnt; ++e) {
        int s0 = csr_src[start + e];
        unsigned int v0 = fp[(size_t)s0 * 64 + lane];
        a0 += bf2f((unsigned short)v0); a1 += bf2f((unsigned short)(v0 >> 16));
    }
    float inv = 1.0f / fmaxf((float)cnt, 1.0f);
    float rx = (a0 + b0 + c0 + d0) * inv;
    float ry = (a1 + b1 + c1 + d1) * inv;
    unsigned int packed = (unsigned int)f2bf(rx) | ((unsigned int)f2bf(ry) << 16);
    ((unsigned int*)out)[(size_t)gid * 64 + lane] = packed;
}

// ---------------- MFMA dual GEMM: out = A1@Wl + A2@Wr + bias ----------------
// A1,A2: [M][128] bf16. Pl,Pr: packed W frags. out: f32 or bf16.
// Block = 4 waves; wave handles 32 rows x NCOL cols. No LDS.

template <int NCOL, bool RELU, bool OUT_BF16>
__global__ __launch_bounds__(BLK) void gemm_mfma_kernel(const unsigned short* __restrict__ A1,
                                                        const unsigned short* __restrict__ A2,
                                                        const unsigned short* __restrict__ Pl,
                                                        const unsigned short* __restrict__ Pr,
                                                        const float* __restrict__ bias,
                                                        void* __restrict__ outp, int M) {
    constexpr int NT = NCOL / 16;
    const int wave = threadIdx.x >> 6, lane = threadIdx.x & 63;
    const int r0 = blockIdx.x * 128 + wave * 32;
    const int arow = lane & 15, kgrp = lane >> 4;

    f32x4 acc[2][NT];
#pragma unroll
    for (int h = 0; h < 2; h++)
#pragma unroll
        for (int n = 0; n < NT; n++) acc[h][n] = (f32x4){0.f, 0.f, 0.f, 0.f};

    const int ra = min(r0 + arow, M - 1);
    const int rb = min(r0 + 16 + arow, M - 1);

#pragma unroll
    for (int mat = 0; mat < 2; ++mat) {
        const unsigned short* A = mat ? A2 : A1;
        const unsigned short* P = mat ? Pr : Pl;
        const unsigned short* Aa = A + (size_t)ra * 128 + kgrp * 8;
        const unsigned short* Ab = A + (size_t)rb * 128 + kgrp * 8;
#pragma unroll
        for (int kb = 0; kb < 4; ++kb) {
            short8 afa = *(const short8*)(Aa + kb * 32);
            short8 afb = *(const short8*)(Ab + kb * 32);
            const unsigned short* Pk = P + (size_t)kb * NT * 512 + lane * 8;
#pragma unroll
            for (int n = 0; n < NT; ++n) {
                short8 wf = *(const short8*)(Pk + n * 512);
                acc[0][n] = __builtin_amdgcn_mfma_f32_16x16x32_bf16(afa, wf, acc[0][n], 0, 0, 0);
                acc[1][n] = __builtin_amdgcn_mfma_f32_16x16x32_bf16(afb, wf, acc[1][n], 0, 0, 0);
            }
        }
    }

    // D layout: col = lane&15, row = (lane>>4)*4 + i
#pragma unroll
    for (int n = 0; n < NT; ++n) {
        int col = n * 16 + arow;
        float bv = bias[col];
#pragma unroll
        for (int h = 0; h < 2; ++h) {
#pragma unroll
            for (int i = 0; i < 4; ++i) {
                int row = r0 + h * 16 + kgrp * 4 + i;
                if (row < M) {
                    float v = acc[h][n][i] + bv;
                    if (RELU) v = fmaxf(v, 0.f);
                    if (OUT_BF16)
                        ((unsigned short*)outp)[(size_t)row * NCOL + col] = f2bf(v);
                    else
                        ((float*)outp)[(size_t)row * NCOL + col] = v;
                }
            }
        }
    }
}

// ---------------- launch ----------------

extern "C" void kernel_launch(void* const* d_in, const int* in_sizes, int n_in,
                              void* d_out, int out_size, void* d_ws, size_t ws_size,
                              hipStream_t stream) {
    const float* x   = (const float*)d_in[0];
    const int*   ei  = (const int*)d_in[1];
    const float* W1l = (const float*)d_in[2];
    const float* W1r = (const float*)d_in[3];
    const float* b1  = (const float*)d_in[4];
    const float* W2l = (const float*)d_in[5];
    const float* W2r = (const float*)d_in[6];
    const float* b2  = (const float*)d_in[7];
    float* out = (float*)d_out;

    const int N = in_sizes[0] / 128;  // 50000
    const int E = in_sizes[1] / 2;    // 800000
    const int* src = ei;
    const int* dst = ei + E;

    char* ws = (char*)d_ws;
    size_t off = 0;
    auto carve = [&](size_t bytes) {
        void* p = ws + off;
        off += (bytes + 255) & ~(size_t)255;
        return p;
    };
    int* deg       = (int*)carve((size_t)N * 4);
    int* cursor    = (int*)carve((size_t)N * 4);
    int* row_start = (int*)carve((size_t)N * 4);
    int* partials  = (int*)carve(256 * 4);
    int* csr_src   = (int*)carve((size_t)E * 4);
    unsigned short* xb   = (unsigned short*)carve((size_t)N * 128 * 2);
    unsigned short* aggb = (unsigned short*)carve((size_t)N * 128 * 2);
    unsigned short* hb   = (unsigned short*)carve((size_t)N * 128 * 2);
    unsigned short* P1l  = (unsigned short*)carve(128 * 128 * 2);
    unsigned short* P1r  = (unsigned short*)carve(128 * 128 * 2);
    unsigned short* P2l  = (unsigned short*)carve(128 * 64 * 2);
    unsigned short* P2r  = (unsigned short*)carve(128 * 64 * 2);

    hipMemsetAsync(deg, 0, (size_t)N * 4, stream);
    hipMemsetAsync(cursor, 0, (size_t)N * 4, stream);

    // conversions + weight packing (tiny)
    const int nquad = N * 128 / 4;
    f32_to_bf16_kernel<<<(nquad + BLK - 1) / BLK, BLK, 0, stream>>>(x, xb, nquad);
    pack_w_kernel<<<(128 * 128 + BLK - 1) / BLK, BLK, 0, stream>>>(W1l, P1l, 128, 128);
    pack_w_kernel<<<(128 * 128 + BLK - 1) / BLK, BLK, 0, stream>>>(W1r, P1r, 128, 128);
    pack_w_kernel<<<(128 * 64 + BLK - 1) / BLK, BLK, 0, stream>>>(W2l, P2l, 128, 64);
    pack_w_kernel<<<(128 * 64 + BLK - 1) / BLK, BLK, 0, stream>>>(W2r, P2r, 128, 64);

    // CSR build
    const int nchunk = (N + BLK - 1) / BLK;  // 196 (<=256)
    deg_count_kernel<<<(E + BLK - 1) / BLK, BLK, 0, stream>>>(dst, E, deg);
    partial_sum_kernel<<<nchunk, BLK, 0, stream>>>(deg, N, partials);
    scan_partials_kernel<<<1, BLK, 0, stream>>>(partials, nchunk);
    chunk_scan_kernel<<<nchunk, BLK, 0, stream>>>(deg, partials, N, row_start);
    fill_kernel<<<(E + BLK - 1) / BLK, BLK, 0, stream>>>(src, dst, E, row_start, cursor, csr_src);

    const int aggGrid = (N + 3) / 4;
    const int gemmGrid = (N + 127) / 128;

    // layer 1: h = relu(agg(x)@W1l + b1 + x@W1r)   (h kept in bf16)
    agg_bf16_kernel<<<aggGrid, BLK, 0, stream>>>(xb, row_start, deg, csr_src, aggb, N);
    gemm_mfma_kernel<128, true, true><<<gemmGrid, BLK, 0, stream>>>(aggb, xb, P1l, P1r, b1, hb, N);
    // layer 2: out = agg(h)@W2l + b2 + h@W2r      (f32 out)
    agg_bf16_kernel<<<aggGrid, BLK, 0, stream>>>(hb, row_start, deg, csr_src, aggb, N);
    gemm_mfma_kernel<64, false, false><<<gemmGrid, BLK, 0, stream>>>(aggb, hb, P2l, P2r, b2, out, N);
}